// Round 11
// baseline (249.143 us; speedup 1.0000x reference)
//
#include <hip/hip_runtime.h>
#include <hip/hip_bf16.h>

// Problem constants
constexpr int B_   = 8;
constexpr int D_   = 1024;
constexpr int T_   = 512;
constexpr int HID_ = 256;
constexpr int NH_  = 4;
constexpr int NL_  = 2;
constexpr float ALPHA_ = 0.2f;
constexpr float EPS_   = 1e-5f;
constexpr float LOG2E_ = 1.4426950408889634f;
constexpr int OUT_ = 64;
constexpr int M_ = B_ * D_;      // 8192 rows
constexpr int DT_ = D_ * T_;     // 524288
constexpr int KIN_ = 2 * T_;     // 1024

typedef __attribute__((ext_vector_type(8))) short short8;   // 8 bf16 (4 VGPRs)
typedef __attribute__((ext_vector_type(4))) float floatx4;  // 4 fp32 acc

__device__ __forceinline__ unsigned short f2bf(float f) {
    unsigned int u = __float_as_uint(f);
    unsigned int r = u + 0x7fffu + ((u >> 16) & 1u);   // round-to-nearest-even
    return (unsigned short)(r >> 16);
}
__device__ __forceinline__ float bf2f(unsigned short u) {
    return __uint_as_float((unsigned int)u << 16);
}
// monotone float<->uint key for atomicMax on signed floats
__device__ __forceinline__ unsigned int kenc(float f) {
    unsigned int u = __float_as_uint(f);
    return (u & 0x80000000u) ? ~u : (u | 0x80000000u);
}
__device__ __forceinline__ float kdec(unsigned int k) {
    unsigned int u = (k & 0x80000000u) ? (k ^ 0x80000000u) : ~k;
    return __uint_as_float(u);
}

// ---------------------------------------------------------------------------
// 1) Fused prep: blocks [0,512): imputation -> Ain bf16 [M][1024]=[X_mean|mask]
//    blocks [512,2560): weight transpose/convert + rmaxkey init
// ---------------------------------------------------------------------------
__global__ __launch_bounds__(256) void prep_k(const float* __restrict__ X,
                                              const float* __restrict__ Mk,
                                              const float* __restrict__ W_in,
                                              const float* __restrict__ gatW,
                                              const float* __restrict__ W_out,
                                              unsigned short* __restrict__ Ain,
                                              unsigned short* __restrict__ Wt_in,
                                              unsigned short* __restrict__ Wcat,
                                              unsigned short* __restrict__ WtO,
                                              unsigned int* __restrict__ rmaxkey) {
    int bx = blockIdx.x;
    if (bx < 512) {
        int idx4 = (bx * 256 + threadIdx.x) * 4;   // over D*T
        int t = idx4 & (T_ - 1);
        int d = idx4 >> 9;
        float4 x[B_], m[B_];
        float4 s = {0, 0, 0, 0}, c = {0, 0, 0, 0};
#pragma unroll
        for (int b = 0; b < B_; b++) {
            x[b] = *(const float4*)&X[(size_t)b * DT_ + idx4];
            m[b] = *(const float4*)&Mk[(size_t)b * DT_ + idx4];
            s.x += x[b].x * m[b].x; s.y += x[b].y * m[b].y;
            s.z += x[b].z * m[b].z; s.w += x[b].w * m[b].w;
            c.x += m[b].x; c.y += m[b].y; c.z += m[b].z; c.w += m[b].w;
        }
        float4 pm;
        pm.x = s.x / (c.x + 1e-10f); pm.y = s.y / (c.y + 1e-10f);
        pm.z = s.z / (c.z + 1e-10f); pm.w = s.w / (c.w + 1e-10f);
#pragma unroll
        for (int b = 0; b < B_; b++) {
            size_t row = (size_t)b * D_ + d;
            ushort4 xm, mk;
            xm.x = f2bf(x[b].x * m[b].x + (1.f - m[b].x) * pm.x);
            xm.y = f2bf(x[b].y * m[b].y + (1.f - m[b].y) * pm.y);
            xm.z = f2bf(x[b].z * m[b].z + (1.f - m[b].z) * pm.z);
            xm.w = f2bf(x[b].w * m[b].w + (1.f - m[b].w) * pm.w);
            mk.x = f2bf(m[b].x); mk.y = f2bf(m[b].y);
            mk.z = f2bf(m[b].z); mk.w = f2bf(m[b].w);
            *(ushort4*)&Ain[row * KIN_ + t]      = xm;
            *(ushort4*)&Ain[row * KIN_ + T_ + t] = mk;
        }
    } else {
        int idx = (bx - 512) * 256 + threadIdx.x;
        if (idx < 64) rmaxkey[idx] = 0u;
        if (idx < 262144) {
            int n = idx >> 10, k = idx & 1023;     // Wt_in[n][k] = W_in[k][n]
            Wt_in[idx] = f2bf(W_in[(size_t)k * HID_ + n]);
        } else if (idx < 393216) {
            int j = idx - 262144;
            int l = j >> 16, n = (j >> 8) & 255, k = j & 255;
            int h = n >> 6, e = n & 63;
            Wcat[j] = f2bf(gatW[(((size_t)(l * NH_ + h) * HID_) + k) * OUT_ + e]);
        } else {
            int j = idx - 393216;
            int n = j >> 8, k = j & 255;           // WtO[n][k] = W_out[k][n]
            WtO[j] = f2bf(W_out[(size_t)k * T_ + n]);
        }
    }
}

// ---------------------------------------------------------------------------
// 2) gemm1: bf16 MFMA GEMM, K=1024, ping-pong staging. BM=64 BN=64 BK=64.
//    Output bf16 + bias. Grid (4, 128).
// ---------------------------------------------------------------------------
__global__ __launch_bounds__(256) void gemm1_k(
        const unsigned short* __restrict__ A,    // M x 1024 bf16
        const unsigned short* __restrict__ Bt,   // 256 x 1024 bf16
        const float* __restrict__ bias,          // 256
        unsigned short* __restrict__ Cb) {       // M x 256 bf16
    __shared__ __align__(16) unsigned short As[2][64 * 72];
    __shared__ __align__(16) unsigned short Bs[2][64 * 72];
    int tid = threadIdx.x;
    int wave = tid >> 6, lane = tid & 63;
    int q = lane >> 4, r16 = lane & 15;
    int rowbase = blockIdx.y * 64;
    int colbase = blockIdx.x * 64;

    int srow = tid >> 3, sk = (tid & 7) * 8;
    const unsigned short* Ap0 = A + (size_t)(rowbase + srow) * KIN_ + sk;
    const unsigned short* Ap1 = A + (size_t)(rowbase + srow + 32) * KIN_ + sk;
    const unsigned short* Bp0 = Bt + (size_t)(colbase + srow) * KIN_ + sk;
    const unsigned short* Bp1 = Bt + (size_t)(colbase + srow + 32) * KIN_ + sk;
    int la0 = srow * 72 + sk, la1 = (srow + 32) * 72 + sk;

    floatx4 acc[4];
#pragma unroll
    for (int i = 0; i < 4; i++) acc[i] = (floatx4)0.f;

    uint4 pa0 = *(const uint4*)Ap0, pa1 = *(const uint4*)Ap1;
    uint4 pb0 = *(const uint4*)Bp0, pb1 = *(const uint4*)Bp1;
    *(uint4*)&As[0][la0] = pa0;
    *(uint4*)&As[0][la1] = pa1;
    *(uint4*)&Bs[0][la0] = pb0;
    *(uint4*)&Bs[0][la1] = pb1;

    for (int it = 0; it < 16; it++) {
        int cur = it & 1;
        __syncthreads();
        if (it + 1 < 16) {
            int kt = (it + 1) << 6;
            pa0 = *(const uint4*)(Ap0 + kt);
            pa1 = *(const uint4*)(Ap1 + kt);
            pb0 = *(const uint4*)(Bp0 + kt);
            pb1 = *(const uint4*)(Bp1 + kt);
        }
#pragma unroll
        for (int t = 0; t < 2; t++) {
            short8 a = *(const short8*)&As[cur][(wave * 16 + r16) * 72 + t * 32 + q * 8];
#pragma unroll
            for (int ni = 0; ni < 4; ni++) {
                short8 b = *(const short8*)&Bs[cur][(ni * 16 + r16) * 72 + t * 32 + q * 8];
                acc[ni] = __builtin_amdgcn_mfma_f32_16x16x32_bf16(a, b, acc[ni], 0, 0, 0);
            }
        }
        if (it + 1 < 16) {
            int nxt = cur ^ 1;
            *(uint4*)&As[nxt][la0] = pa0;
            *(uint4*)&As[nxt][la1] = pa1;
            *(uint4*)&Bs[nxt][la0] = pb0;
            *(uint4*)&Bs[nxt][la1] = pb1;
        }
    }
#pragma unroll
    for (int rr = 0; rr < 4; rr++) {
        int row = rowbase + wave * 16 + q * 4 + rr;
#pragma unroll
        for (int ni = 0; ni < 4; ni++) {
            int col = colbase + ni * 16 + r16;
            Cb[(size_t)row * HID_ + col] = f2bf(acc[ni][rr] + bias[col]);
        }
    }
}

// ---------------------------------------------------------------------------
// 3) Small-K GEMM (K=256, whole tile in LDS, ONE barrier).
//    LNF: A = bf16(LN(h + (pacc0+pacc1)/den)) computed in prologue (block
//         x==0 optionally writes normalized h to hOut).
//    EPI==2: hwT[bh][e][m] + fused s_l/s_r/rmax.  EPI==0: fp32 C + bias.
// ---------------------------------------------------------------------------
template <bool LNF, int EPI>
__global__ __launch_bounds__(256) void gemm_small_k(
        const unsigned short* __restrict__ Ah,   // h bf16 [M][256]
        const float* __restrict__ pacc,          // LNF
        const float* __restrict__ pden,          // LNF
        const float* __restrict__ lng,           // LNF
        const float* __restrict__ lnb,           // LNF
        unsigned short* __restrict__ hOut,       // LNF: write h' (x==0), or null
        const unsigned short* __restrict__ Bt,   // [N][256] bf16
        const float* __restrict__ bias,          // EPI==0
        float* __restrict__ C,                   // EPI==0
        unsigned short* __restrict__ hwT,        // EPI==2
        const float* __restrict__ ga,            // EPI==2: gat_a + l*512
        float* __restrict__ s_l,
        float* __restrict__ s_r,
        unsigned int* __restrict__ rmaxkey,      // EPI==2: + l*32
        int Nsz) {
    constexpr int STR = 264;   // 256 + 8 pad
    __shared__ __align__(16) unsigned short As[64 * STR];  // 33 KB
    __shared__ __align__(16) unsigned short Bs[64 * STR];  // 33 KB
    int tid = threadIdx.x;
    int wave = tid >> 6, lane = tid & 63;
    int q = lane >> 4, r16 = lane & 15;
    int rowbase = blockIdx.y * 64;
    int colbase = blockIdx.x * 64;

    // stage B: 64 x 256, 8 x 16B per thread
#pragma unroll
    for (int i = 0; i < 8; i++) {
        int s = tid + i * 256;
        int n = s >> 5, part = s & 31;
        *(uint4*)&Bs[n * STR + part * 8] =
            *(const uint4*)&Bt[(size_t)(colbase + n) * HID_ + part * 8];
    }
    // stage A
    if constexpr (!LNF) {
#pragma unroll
        for (int i = 0; i < 8; i++) {
            int s = tid + i * 256;
            int r = s >> 5, part = s & 31;
            *(uint4*)&As[r * STR + part * 8] =
                *(const uint4*)&Ah[(size_t)(rowbase + r) * HID_ + part * 8];
        }
    } else {
        float4 gg = *(const float4*)&lng[lane * 4];
        float4 bbv = *(const float4*)&lnb[lane * 4];
        int hh = lane >> 4;
        bool wr = (hOut != nullptr) && (blockIdx.x == 0);
#pragma unroll 4
        for (int i = 0; i < 16; i++) {
            size_t row = (size_t)rowbase + wave * 16 + i;
            ushort4 hb = *(const ushort4*)&Ah[row * HID_ + lane * 4];
            float4 p0 = *(const float4*)&pacc[row * HID_ + lane * 4];
            float4 p1 = *(const float4*)&pacc[((size_t)M_ + row) * HID_ + lane * 4];
            float den = pden[row * NH_ + hh] + pden[((size_t)M_ + row) * NH_ + hh];
            float inv = 1.f / den;
            float4 v = {bf2f(hb.x) + (p0.x + p1.x) * inv,
                        bf2f(hb.y) + (p0.y + p1.y) * inv,
                        bf2f(hb.z) + (p0.z + p1.z) * inv,
                        bf2f(hb.w) + (p0.w + p1.w) * inv};
            float s = v.x + v.y + v.z + v.w;
#pragma unroll
            for (int off = 1; off < 64; off <<= 1) s += __shfl_xor(s, off, 64);
            float mu = s * (1.f / HID_);
            float4 d = {v.x - mu, v.y - mu, v.z - mu, v.w - mu};
            float s2 = d.x * d.x + d.y * d.y + d.z * d.z + d.w * d.w;
#pragma unroll
            for (int off = 1; off < 64; off <<= 1) s2 += __shfl_xor(s2, off, 64);
            float rs = rsqrtf(s2 * (1.f / HID_) + EPS_);
            ushort4 pk;
            pk.x = f2bf(d.x * rs * gg.x + bbv.x);
            pk.y = f2bf(d.y * rs * gg.y + bbv.y);
            pk.z = f2bf(d.z * rs * gg.z + bbv.z);
            pk.w = f2bf(d.w * rs * gg.w + bbv.w);
            *(ushort4*)&As[(wave * 16 + i) * STR + lane * 4] = pk;
            if (wr) *(ushort4*)&hOut[row * HID_ + lane * 4] = pk;
        }
    }
    __syncthreads();   // the ONLY barrier

    floatx4 acc[4];
#pragma unroll
    for (int i = 0; i < 4; i++) acc[i] = (floatx4)0.f;
#pragma unroll
    for (int kk = 0; kk < 8; kk++) {
        short8 a = *(const short8*)&As[(wave * 16 + r16) * STR + kk * 32 + q * 8];
#pragma unroll
        for (int ni = 0; ni < 4; ni++) {
            short8 b = *(const short8*)&Bs[(ni * 16 + r16) * STR + kk * 32 + q * 8];
            acc[ni] = __builtin_amdgcn_mfma_f32_16x16x32_bf16(a, b, acc[ni], 0, 0, 0);
        }
    }

    // ---- epilogue. C/D map: col=lane&15, row=(lane>>4)*4+reg ----
    if constexpr (EPI == 2) {
        int bhh = ((rowbase >> 10) << 2) + blockIdx.x;   // b*4 + h
        int nb = (rowbase & (D_ - 1)) + wave * 16;
#pragma unroll
        for (int ni = 0; ni < 4; ni++) {
            int e = ni * 16 + r16;
            ushort4 pk;
            pk.x = f2bf(acc[ni][0]);
            pk.y = f2bf(acc[ni][1]);
            pk.z = f2bf(acc[ni][2]);
            pk.w = f2bf(acc[ni][3]);
            *(ushort4*)&hwT[((size_t)(bhh * 64 + e) << 10) + nb + q * 4] = pk;
        }
        const float* gab = ga + blockIdx.x * 2 * OUT_;
        float al4[4], ar4[4];
#pragma unroll
        for (int ni = 0; ni < 4; ni++) {
            al4[ni] = gab[ni * 16 + r16];
            ar4[ni] = gab[OUT_ + ni * 16 + r16];
        }
        float slv[4], srv[4];
#pragma unroll
        for (int rr = 0; rr < 4; rr++) {
            float s1 = 0.f, s2 = 0.f;
#pragma unroll
            for (int ni = 0; ni < 4; ni++) {
                s1 += acc[ni][rr] * al4[ni];
                s2 += acc[ni][rr] * ar4[ni];
            }
            slv[rr] = s1;
            srv[rr] = s2;
        }
#pragma unroll
        for (int off = 1; off < 16; off <<= 1) {
#pragma unroll
            for (int rr = 0; rr < 4; rr++) {
                slv[rr] += __shfl_xor(slv[rr], off, 64);
                srv[rr] += __shfl_xor(srv[rr], off, 64);
            }
        }
        {
            int rsel = r16 & 3;
            float sv = (rsel == 0) ? slv[0] : (rsel == 1) ? slv[1] : (rsel == 2) ? slv[2] : slv[3];
            float rv = (rsel == 0) ? srv[0] : (rsel == 1) ? srv[1] : (rsel == 2) ? srv[2] : srv[3];
            int n = nb + q * 4 + rsel;
            if (r16 < 4)                   s_l[bhh * D_ + n] = sv;
            else if (r16 >= 8 && r16 < 12) s_r[bhh * D_ + n] = rv;
        }
        float mx = fmaxf(fmaxf(srv[0], srv[1]), fmaxf(srv[2], srv[3]));
        mx = fmaxf(mx, __shfl_xor(mx, 16, 64));
        mx = fmaxf(mx, __shfl_xor(mx, 32, 64));
        if (lane == 0) atomicMax(&rmaxkey[bhh], kenc(mx));
    } else {
#pragma unroll
        for (int rr = 0; rr < 4; rr++) {
            int row = rowbase + wave * 16 + q * 4 + rr;
#pragma unroll
            for (int ni = 0; ni < 4; ni++) {
                int col = colbase + ni * 16 + r16;
                C[(size_t)row * Nsz + col] = acc[ni][rr] + bias[col];
            }
        }
    }
}

// ---------------------------------------------------------------------------
// 4) Attention via MFMA, split-m 2-way, exp2 softmax (R7/R10-proven shape).
//    grid (32 bh, 16 rowblocks, 2 halves) = 1024 blocks, 256 thr.
// ---------------------------------------------------------------------------
__global__ __launch_bounds__(256) void attn_k(const unsigned short* __restrict__ hwT,
                                              const float* __restrict__ sl_g,
                                              const float* __restrict__ sr_g,
                                              const unsigned int* __restrict__ rmaxkey,
                                              float* __restrict__ pacc,
                                              float* __restrict__ pden) {
    int bh = blockIdx.x;
    int b = bh >> 2, h = bh & 3;
    int half = blockIdx.z;
    int mb = half * 512;
    int tid = threadIdx.x;
    int wave = tid >> 6, lane = tid & 63;
    int q = lane >> 4, r16 = lane & 15;

    __shared__ float srs[512];                                // 2 KB (log2e-scaled)
    __shared__ __align__(16) unsigned short Vt[2][64][136];   // 34 KB ping-pong

    {
        float2 sv = *(const float2*)&sr_g[bh * D_ + mb + tid * 2];
        sv.x *= LOG2E_; sv.y *= LOG2E_;
        *(float2*)&srs[tid * 2] = sv;
    }

    float rm = kdec(rmaxkey[bh]) * LOG2E_;
    int row0 = blockIdx.y * 64 + wave * 16;
    float sl = sl_g[bh * D_ + row0 + r16] * LOG2E_;
    float xm = sl + rm;
    float Mn = fmaxf(xm, ALPHA_ * xm);   // leaky-relu positively homogeneous

    floatx4 acc[4];
#pragma unroll
    for (int i = 0; i < 4; i++) acc[i] = (floatx4)0.f;
    float dsum = 0.f;

    const unsigned short* vbase = hwT + ((size_t)(bh * 64) << 10) + mb;
    int se[4], sp[4];
#pragma unroll
    for (int i = 0; i < 4; i++) {
        int s = tid + i * 256;
        se[i] = s >> 4;
        sp[i] = (s & 15) * 8;
    }

    uint4 pre[4];
#pragma unroll
    for (int i = 0; i < 4; i++)
        pre[i] = *(const uint4*)&vbase[((size_t)se[i] << 10) + sp[i]];
#pragma unroll
    for (int i = 0; i < 4; i++)
        *(uint4*)&Vt[0][se[i]][sp[i]] = pre[i];
    __syncthreads();   // covers srs + buffer 0

    for (int c = 0; c < 4; c++) {
        int cur = c & 1;
        if (c < 3) {
            int mo = (c + 1) * 128;
#pragma unroll
            for (int i = 0; i < 4; i++)
                pre[i] = *(const uint4*)&vbase[((size_t)se[i] << 10) + mo + sp[i]];
        }
#pragma unroll
        for (int kk = 0; kk < 128; kk += 32) {
            int m0 = c * 128 + kk + q * 8;
            float4 s0 = *(const float4*)&srs[m0];
            float4 s1 = *(const float4*)&srs[m0 + 4];
            float sr8[8] = {s0.x, s0.y, s0.z, s0.w, s1.x, s1.y, s1.z, s1.w};
            float p[8];
#pragma unroll
            for (int j = 0; j < 8; j++) {
                float x = sl + sr8[j];
                float e = fmaxf(x, ALPHA_ * x);
                float pj = exp2f(e - Mn);
                dsum += pj;
                p[j] = pj;
            }
            union { unsigned int u[4]; short8 s8; } cv;
#pragma unroll
            for (int j = 0; j < 4; j++) {
                unsigned int lo = (__float_as_uint(p[2 * j]) + 0x8000u) >> 16;
                unsigned int hi = (__float_as_uint(p[2 * j + 1]) + 0x8000u) & 0xffff0000u;
                cv.u[j] = hi | lo;
            }
#pragma unroll
            for (int ni = 0; ni < 4; ni++) {
                short8 bfr = *(const short8*)&Vt[cur][ni * 16 + r16][kk + q * 8];
                acc[ni] = __builtin_amdgcn_mfma_f32_16x16x32_bf16(cv.s8, bfr, acc[ni], 0, 0, 0);
            }
        }
        if (c < 3) {
#pragma unroll
            for (int i = 0; i < 4; i++)
                *(uint4*)&Vt[cur ^ 1][se[i]][sp[i]] = pre[i];
        }
        __syncthreads();
    }
    dsum += __shfl_xor(dsum, 16);
    dsum += __shfl_xor(dsum, 32);
    size_t gr0 = (size_t)b * D_ + row0;
    if (lane < 16) pden[((size_t)half * M_ + gr0 + r16) * NH_ + h] = dsum;
#pragma unroll
    for (int rr = 0; rr < 4; rr++) {
        size_t grow = gr0 + q * 4 + rr;
#pragma unroll
        for (int ni = 0; ni < 4; ni++) {
            pacc[((size_t)half * M_ + grow) * HID_ + h * OUT_ + ni * 16 + r16] = acc[ni][rr];
        }
    }
}

// ---------------------------------------------------------------------------
extern "C" void kernel_launch(void* const* d_in, const int* in_sizes, int n_in,
                              void* d_out, int out_size, void* d_ws, size_t ws_size,
                              hipStream_t stream) {
    const float* X_obs = (const float*)d_in[0];
    const float* mask  = (const float*)d_in[1];
    const float* W_in  = (const float*)d_in[2];
    const float* b_in  = (const float*)d_in[3];
    const float* gat_W = (const float*)d_in[4];
    const float* gat_a = (const float*)d_in[5];
    const float* ln_g  = (const float*)d_in[6];
    const float* ln_b  = (const float*)d_in[7];
    const float* W_out = (const float*)d_in[8];
    const float* b_out = (const float*)d_in[9];
    float* out = (float*)d_out;

    // Workspace layout (~34 MB):
    //  [0,16M):   Ain bf16 (M x 1024); dead after gemm1, then:
    //             hwT bf16 [32][64][1024] at [0,4M), pacc fp32 [2][M][256] at [4,20M)
    //  [20M,+):   pden fp32 [2][M][4] (256 KB)
    //  [21M,25M): hbfA bf16 (M x 256)  -- h0
    //  [25M,29M): hbfB bf16 (M x 256)  -- h1 (written by layer-1 LN prologue)
    //  [29M,+):   Wt_in, Wcat, WtO (bf16), slb/srb (fp32), rmaxkey (uint[64])
    char* base = (char*)d_ws;
    unsigned short* Ain  = (unsigned short*)base;
    unsigned short* hwT  = (unsigned short*)base;
    float* pacc = (float*)(base + (4u << 20));
    float* pden = (float*)(base + (20u << 20));
    unsigned short* hbfA  = (unsigned short*)(base + (21u << 20));
    unsigned short* hbfB  = (unsigned short*)(base + (25u << 20));
    unsigned short* Wt_in = (unsigned short*)(base + (29u << 20));
    unsigned short* Wcat  = Wt_in + (size_t)HID_ * KIN_;        // 256*1024
    unsigned short* WtO   = Wcat + (size_t)NL_ * HID_ * HID_;   // 2*256*256
    float* slb = (float*)(WtO + (size_t)T_ * HID_);             // 32*1024
    float* srb = slb + B_ * NH_ * D_;
    unsigned int* rmaxkey = (unsigned int*)(srb + B_ * NH_ * D_);  // [2][32]

    prep_k<<<2560, 256, 0, stream>>>(X_obs, mask, W_in, gat_W, W_out,
                                     Ain, Wt_in, Wcat, WtO, rmaxkey);

    // h0 = [X_mean|mask] @ W_in + b_in  -> hbfA
    gemm1_k<<<dim3(HID_ / 64, M_ / 64), 256, 0, stream>>>(Ain, Wt_in, b_in, hbfA);

    // layer 0: hW0 = h0 @ Wcat[0]  (+ s_l/s_r/rmax)
    gemm_small_k<false, 2><<<dim3(HID_ / 64, M_ / 64), 256, 0, stream>>>(
        hbfA, nullptr, nullptr, nullptr, nullptr, nullptr,
        Wcat, nullptr, nullptr, hwT, gat_a, slb, srb, rmaxkey, HID_);
    attn_k<<<dim3(B_ * NH_, D_ / 64, 2), 256, 0, stream>>>(
        hwT, slb, srb, rmaxkey, pacc, pden);

    // layer 1: h1 = LN0(h0 + attn0) (fused prologue, x==0 writes hbfB);
    //          hW1 = h1 @ Wcat[1]  (+ s_l/s_r/rmax)
    gemm_small_k<true, 2><<<dim3(HID_ / 64, M_ / 64), 256, 0, stream>>>(
        hbfA, pacc, pden, ln_g, ln_b, hbfB,
        Wcat + (size_t)HID_ * HID_, nullptr, nullptr, hwT,
        gat_a + (size_t)NH_ * 2 * OUT_, slb, srb, rmaxkey + 32, HID_);
    attn_k<<<dim3(B_ * NH_, D_ / 64, 2), 256, 0, stream>>>(
        hwT, slb, srb, rmaxkey + 32, pacc, pden);

    // out = LN1(h1 + attn1) @ W_out + b_out  (LN fused prologue), fp32 out
    gemm_small_k<true, 0><<<dim3(T_ / 64, M_ / 64), 256, 0, stream>>>(
        hbfB, pacc, pden, ln_g + HID_, ln_b + HID_, nullptr,
        WtO, b_out, out, nullptr, nullptr, nullptr, nullptr, nullptr, T_);
}

// Round 12
// 215.642 us; speedup vs baseline: 1.1554x; 1.1554x over previous
//
#include <hip/hip_runtime.h>
#include <hip/hip_bf16.h>

// Problem constants
constexpr int B_   = 8;
constexpr int D_   = 1024;
constexpr int T_   = 512;
constexpr int HID_ = 256;
constexpr int NH_  = 4;
constexpr int NL_  = 2;
constexpr float ALPHA_ = 0.2f;
constexpr float EPS_   = 1e-5f;
constexpr int OUT_ = 64;
constexpr int M_ = B_ * D_;      // 8192 rows
constexpr int DT_ = D_ * T_;     // 524288
constexpr int KIN_ = 2 * T_;     // 1024

typedef __attribute__((ext_vector_type(8))) short short8;   // 8 bf16 (4 VGPRs)
typedef __attribute__((ext_vector_type(4))) float floatx4;  // 4 fp32 acc

__device__ __forceinline__ unsigned short f2bf(float f) {
    unsigned int u = __float_as_uint(f);
    unsigned int r = u + 0x7fffu + ((u >> 16) & 1u);   // round-to-nearest-even
    return (unsigned short)(r >> 16);
}
// monotone float<->uint key for atomicMax on signed floats
__device__ __forceinline__ unsigned int kenc(float f) {
    unsigned int u = __float_as_uint(f);
    return (u & 0x80000000u) ? ~u : (u | 0x80000000u);
}
__device__ __forceinline__ float kdec(unsigned int k) {
    unsigned int u = (k & 0x80000000u) ? (k ^ 0x80000000u) : ~k;
    return __uint_as_float(u);
}

// ---------------------------------------------------------------------------
// 1) Fused prep: blocks [0,512): imputation -> Ain bf16 [M][1024]=[X_mean|mask]
//    blocks [512,2560): weight transpose/convert + rmaxkey init
// ---------------------------------------------------------------------------
__global__ __launch_bounds__(256) void prep_k(const float* __restrict__ X,
                                              const float* __restrict__ Mk,
                                              const float* __restrict__ W_in,
                                              const float* __restrict__ gatW,
                                              const float* __restrict__ W_out,
                                              unsigned short* __restrict__ Ain,
                                              unsigned short* __restrict__ Wt_in,
                                              unsigned short* __restrict__ Wcat,
                                              unsigned short* __restrict__ WtO,
                                              unsigned int* __restrict__ rmaxkey) {
    int bx = blockIdx.x;
    if (bx < 512) {
        int idx4 = (bx * 256 + threadIdx.x) * 4;   // over D*T
        int t = idx4 & (T_ - 1);
        int d = idx4 >> 9;
        float4 x[B_], m[B_];
        float4 s = {0, 0, 0, 0}, c = {0, 0, 0, 0};
#pragma unroll
        for (int b = 0; b < B_; b++) {
            x[b] = *(const float4*)&X[(size_t)b * DT_ + idx4];
            m[b] = *(const float4*)&Mk[(size_t)b * DT_ + idx4];
            s.x += x[b].x * m[b].x; s.y += x[b].y * m[b].y;
            s.z += x[b].z * m[b].z; s.w += x[b].w * m[b].w;
            c.x += m[b].x; c.y += m[b].y; c.z += m[b].z; c.w += m[b].w;
        }
        float4 pm;
        pm.x = s.x / (c.x + 1e-10f); pm.y = s.y / (c.y + 1e-10f);
        pm.z = s.z / (c.z + 1e-10f); pm.w = s.w / (c.w + 1e-10f);
#pragma unroll
        for (int b = 0; b < B_; b++) {
            size_t row = (size_t)b * D_ + d;
            ushort4 xm, mk;
            xm.x = f2bf(x[b].x * m[b].x + (1.f - m[b].x) * pm.x);
            xm.y = f2bf(x[b].y * m[b].y + (1.f - m[b].y) * pm.y);
            xm.z = f2bf(x[b].z * m[b].z + (1.f - m[b].z) * pm.z);
            xm.w = f2bf(x[b].w * m[b].w + (1.f - m[b].w) * pm.w);
            mk.x = f2bf(m[b].x); mk.y = f2bf(m[b].y);
            mk.z = f2bf(m[b].z); mk.w = f2bf(m[b].w);
            *(ushort4*)&Ain[row * KIN_ + t]      = xm;
            *(ushort4*)&Ain[row * KIN_ + T_ + t] = mk;
        }
    } else {
        int idx = (bx - 512) * 256 + threadIdx.x;
        if (idx < 64) rmaxkey[idx] = 0u;
        if (idx < 262144) {
            int n = idx >> 10, k = idx & 1023;     // Wt_in[n][k] = W_in[k][n]
            Wt_in[idx] = f2bf(W_in[(size_t)k * HID_ + n]);
        } else if (idx < 393216) {
            int j = idx - 262144;
            int l = j >> 16, n = (j >> 8) & 255, k = j & 255;
            int h = n >> 6, e = n & 63;
            Wcat[j] = f2bf(gatW[(((size_t)(l * NH_ + h) * HID_) + k) * OUT_ + e]);
        } else {
            int j = idx - 393216;
            int n = j >> 8, k = j & 255;           // WtO[n][k] = W_out[k][n]
            WtO[j] = f2bf(W_out[(size_t)k * T_ + n]);
        }
    }
}

// ---------------------------------------------------------------------------
// 2) bf16 MFMA GEMM. BM=64 BN=64 BK=64, 4 waves, wave = 16 rows x 64 cols.
//    Padded LDS (stride 72) kills bank conflicts; reg-staged ping-pong.
//    MODE 0: fp32 C (+bias). MODE 1: + bf16 copy. MODE 2: hwT + s_l/s_r/rmax.
// ---------------------------------------------------------------------------
template <int MODE>
__global__ __launch_bounds__(256) void gemm_bf16_k(
        const unsigned short* __restrict__ A,    // M x K bf16
        const unsigned short* __restrict__ Bt,   // N x K bf16 (B transposed)
        const float* __restrict__ bias,          // N or null (MODE 0/1)
        float* __restrict__ C,                   // M x N fp32 (MODE 0/1)
        unsigned short* __restrict__ Cb,         // bf16 copy (MODE1) / hwT (MODE2)
        const float* __restrict__ ga,            // gat_a + l*512 (MODE2)
        float* __restrict__ s_l,                 // (MODE2)
        float* __restrict__ s_r,                 // (MODE2)
        unsigned int* __restrict__ rmaxkey,      // + l*32 (MODE2)
        int Nsz, int Ksz) {
    __shared__ __align__(16) unsigned short As[2][64 * 72];  // 18 KB, padded
    __shared__ __align__(16) unsigned short Bs[2][64 * 72];  // 18 KB
    int tid = threadIdx.x;
    int wave = tid >> 6, lane = tid & 63;
    int q = lane >> 4, r16 = lane & 15;
    int rowbase = blockIdx.y * 64;
    int colbase = blockIdx.x * 64;

    int srow = tid >> 3, sk = (tid & 7) * 8;         // staging slot
    const unsigned short* Ap0 = A + (size_t)(rowbase + srow) * Ksz + sk;
    const unsigned short* Ap1 = A + (size_t)(rowbase + srow + 32) * Ksz + sk;
    const unsigned short* Bp0 = Bt + (size_t)(colbase + srow) * Ksz + sk;
    const unsigned short* Bp1 = Bt + (size_t)(colbase + srow + 32) * Ksz + sk;
    int la0 = srow * 72 + sk, la1 = (srow + 32) * 72 + sk;

    floatx4 acc[4];
#pragma unroll
    for (int i = 0; i < 4; i++) acc[i] = (floatx4)0.f;

    uint4 pa0 = *(const uint4*)Ap0, pa1 = *(const uint4*)Ap1;
    uint4 pb0 = *(const uint4*)Bp0, pb1 = *(const uint4*)Bp1;
    *(uint4*)&As[0][la0] = pa0;
    *(uint4*)&As[0][la1] = pa1;
    *(uint4*)&Bs[0][la0] = pb0;
    *(uint4*)&Bs[0][la1] = pb1;

    int nk = Ksz >> 6;
    for (int it = 0; it < nk; it++) {
        int cur = it & 1;
        __syncthreads();
        if (it + 1 < nk) {
            int kt = (it + 1) << 6;
            pa0 = *(const uint4*)(Ap0 + kt);
            pa1 = *(const uint4*)(Ap1 + kt);
            pb0 = *(const uint4*)(Bp0 + kt);
            pb1 = *(const uint4*)(Bp1 + kt);
        }
#pragma unroll
        for (int t = 0; t < 2; t++) {
            short8 a = *(const short8*)&As[cur][(wave * 16 + r16) * 72 + t * 32 + q * 8];
#pragma unroll
            for (int ni = 0; ni < 4; ni++) {
                short8 b = *(const short8*)&Bs[cur][(ni * 16 + r16) * 72 + t * 32 + q * 8];
                acc[ni] = __builtin_amdgcn_mfma_f32_16x16x32_bf16(a, b, acc[ni], 0, 0, 0);
            }
        }
        if (it + 1 < nk) {
            int nxt = cur ^ 1;
            *(uint4*)&As[nxt][la0] = pa0;
            *(uint4*)&As[nxt][la1] = pa1;
            *(uint4*)&Bs[nxt][la0] = pb0;
            *(uint4*)&Bs[nxt][la1] = pb1;
        }
    }
    // ---- epilogue. C/D map: col=lane&15, row=(lane>>4)*4+reg ----
    if constexpr (MODE == 2) {
        int bhh = ((rowbase >> 10) << 2) + blockIdx.x;   // b*4 + h
        int nb = (rowbase & (D_ - 1)) + wave * 16;
        // hwT[bh][e][m] bf16
#pragma unroll
        for (int ni = 0; ni < 4; ni++) {
            int e = ni * 16 + r16;
            ushort4 pk;
            pk.x = f2bf(acc[ni][0]);
            pk.y = f2bf(acc[ni][1]);
            pk.z = f2bf(acc[ni][2]);
            pk.w = f2bf(acc[ni][3]);
            *(ushort4*)&Cb[((size_t)(bhh * 64 + e) << 10) + nb + q * 4] = pk;
        }
        // fused s_l/s_r from fp32 acc
        const float* gab = ga + blockIdx.x * 2 * OUT_;
        float al4[4], ar4[4];
#pragma unroll
        for (int ni = 0; ni < 4; ni++) {
            al4[ni] = gab[ni * 16 + r16];
            ar4[ni] = gab[OUT_ + ni * 16 + r16];
        }
        float slv[4], srv[4];
#pragma unroll
        for (int rr = 0; rr < 4; rr++) {
            float s1 = 0.f, s2 = 0.f;
#pragma unroll
            for (int ni = 0; ni < 4; ni++) {
                s1 += acc[ni][rr] * al4[ni];
                s2 += acc[ni][rr] * ar4[ni];
            }
            slv[rr] = s1;
            srv[rr] = s2;
        }
#pragma unroll
        for (int off = 1; off < 16; off <<= 1) {
#pragma unroll
            for (int rr = 0; rr < 4; rr++) {
                slv[rr] += __shfl_xor(slv[rr], off, 64);
                srv[rr] += __shfl_xor(srv[rr], off, 64);
            }
        }
        {
            int rsel = r16 & 3;
            float sv = (rsel == 0) ? slv[0] : (rsel == 1) ? slv[1] : (rsel == 2) ? slv[2] : slv[3];
            float rv = (rsel == 0) ? srv[0] : (rsel == 1) ? srv[1] : (rsel == 2) ? srv[2] : srv[3];
            int n = nb + q * 4 + rsel;
            if (r16 < 4)                 s_l[bhh * D_ + n] = sv;
            else if (r16 >= 8 && r16 < 12) s_r[bhh * D_ + n] = rv;
        }
        float mx = fmaxf(fmaxf(srv[0], srv[1]), fmaxf(srv[2], srv[3]));
        mx = fmaxf(mx, __shfl_xor(mx, 16, 64));
        mx = fmaxf(mx, __shfl_xor(mx, 32, 64));
        if (lane == 0) atomicMax(&rmaxkey[bhh], kenc(mx));
    } else {
#pragma unroll
        for (int rr = 0; rr < 4; rr++) {
            int row = rowbase + wave * 16 + q * 4 + rr;
#pragma unroll
            for (int ni = 0; ni < 4; ni++) {
                int col = colbase + ni * 16 + r16;
                float v = acc[ni][rr] + (bias ? bias[col] : 0.f);
                C[(size_t)row * Nsz + col] = v;
                if constexpr (MODE == 1) Cb[(size_t)row * Nsz + col] = f2bf(v);
            }
        }
    }
}

// ---------------------------------------------------------------------------
// 3) Attention via MFMA, split-m 2-way. grid (32 bh, 16 rowblocks, 2 halves),
//    256 thr, 4 waves; wave = 16 rows x half the m-range. Writes partial
//    acc (pacc) and denominator (pden); addln combines exactly.
// ---------------------------------------------------------------------------
__global__ __launch_bounds__(256) void attn_k(const unsigned short* __restrict__ hwT,
                                              const float* __restrict__ sl_g,
                                              const float* __restrict__ sr_g,
                                              const unsigned int* __restrict__ rmaxkey,
                                              float* __restrict__ pacc,
                                              float* __restrict__ pden) {
    int bh = blockIdx.x;
    int b = bh >> 2, h = bh & 3;
    int half = blockIdx.z;
    int mb = half * 512;
    int tid = threadIdx.x;
    int wave = tid >> 6, lane = tid & 63;
    int q = lane >> 4, r16 = lane & 15;

    __shared__ float srs[512];                                // 2 KB
    __shared__ __align__(16) unsigned short Vt[2][64][136];   // 34 KB ping-pong

    *(float2*)&srs[tid * 2] = *(const float2*)&sr_g[bh * D_ + mb + tid * 2];

    float rm = kdec(rmaxkey[bh]);
    int row0 = blockIdx.y * 64 + wave * 16;
    float sl = sl_g[bh * D_ + row0 + r16];
    float xm = sl + rm;
    float Mn = fmaxf(xm, ALPHA_ * xm);

    floatx4 acc[4];
#pragma unroll
    for (int i = 0; i < 4; i++) acc[i] = (floatx4)0.f;
    float dsum = 0.f;

    const unsigned short* vbase = hwT + ((size_t)(bh * 64) << 10) + mb;
    int se[4], sp[4];
#pragma unroll
    for (int i = 0; i < 4; i++) {
        int s = tid + i * 256;
        se[i] = s >> 4;
        sp[i] = (s & 15) * 8;
    }

    uint4 pre[4];
#pragma unroll
    for (int i = 0; i < 4; i++)
        pre[i] = *(const uint4*)&vbase[((size_t)se[i] << 10) + sp[i]];
#pragma unroll
    for (int i = 0; i < 4; i++)
        *(uint4*)&Vt[0][se[i]][sp[i]] = pre[i];
    __syncthreads();   // covers srs + buffer 0

    for (int c = 0; c < 4; c++) {
        int cur = c & 1;
        if (c < 3) {
            int mo = (c + 1) * 128;
#pragma unroll
            for (int i = 0; i < 4; i++)
                pre[i] = *(const uint4*)&vbase[((size_t)se[i] << 10) + mo + sp[i]];
        }
#pragma unroll
        for (int kk = 0; kk < 128; kk += 32) {
            int m0 = c * 128 + kk + q * 8;
            float4 s0 = *(const float4*)&srs[m0];
            float4 s1 = *(const float4*)&srs[m0 + 4];
            float sr8[8] = {s0.x, s0.y, s0.z, s0.w, s1.x, s1.y, s1.z, s1.w};
            float p[8];
#pragma unroll
            for (int j = 0; j < 8; j++) {
                float x = sl + sr8[j];
                float e = fmaxf(x, ALPHA_ * x);
                float pj = __expf(e - Mn);
                dsum += pj;
                p[j] = pj;
            }
            union { unsigned int u[4]; short8 s8; } cv;
#pragma unroll
            for (int j = 0; j < 4; j++) {
                unsigned int lo = (__float_as_uint(p[2 * j]) + 0x8000u) >> 16;
                unsigned int hi = (__float_as_uint(p[2 * j + 1]) + 0x8000u) & 0xffff0000u;
                cv.u[j] = hi | lo;
            }
#pragma unroll
            for (int ni = 0; ni < 4; ni++) {
                short8 bfr = *(const short8*)&Vt[cur][ni * 16 + r16][kk + q * 8];
                acc[ni] = __builtin_amdgcn_mfma_f32_16x16x32_bf16(cv.s8, bfr, acc[ni], 0, 0, 0);
            }
        }
        if (c < 3) {
#pragma unroll
            for (int i = 0; i < 4; i++)
                *(uint4*)&Vt[cur ^ 1][se[i]][sp[i]] = pre[i];
        }
        __syncthreads();
    }
    dsum += __shfl_xor(dsum, 16);
    dsum += __shfl_xor(dsum, 32);
    size_t gr0 = (size_t)b * D_ + row0;
    if (lane < 16) pden[((size_t)half * M_ + gr0 + r16) * NH_ + h] = dsum;
#pragma unroll
    for (int rr = 0; rr < 4; rr++) {
        size_t grow = gr0 + q * 4 + rr;
#pragma unroll
        for (int ni = 0; ni < 4; ni++) {
            pacc[((size_t)half * M_ + grow) * HID_ + h * OUT_ + ni * 16 + r16] = acc[ni][rr];
        }
    }
}

// ---------------------------------------------------------------------------
// 4) h = LayerNorm(h + (pacc0+pacc1)/(pden0+pden1))*g + b; fp32 + bf16 out.
//    One wave per row, shfl-only reductions. grid 2048 x 256.
// ---------------------------------------------------------------------------
__global__ __launch_bounds__(256) void addln_k(float* __restrict__ h,
                                               const float* __restrict__ pacc,
                                               const float* __restrict__ pden,
                                               const float* __restrict__ g,
                                               const float* __restrict__ bb,
                                               unsigned short* __restrict__ hbf) {
    int wave = threadIdx.x >> 6, lane = threadIdx.x & 63;
    size_t row = (size_t)blockIdx.x * 4 + wave;
    float4 a  = *(const float4*)&h[row * HID_ + lane * 4];
    float4 p0 = *(const float4*)&pacc[row * HID_ + lane * 4];
    float4 p1 = *(const float4*)&pacc[((size_t)M_ + row) * HID_ + lane * 4];
    int hh = lane >> 4;
    float den = pden[row * NH_ + hh] + pden[((size_t)M_ + row) * NH_ + hh];
    float inv = 1.f / den;
    float4 v = {a.x + (p0.x + p1.x) * inv, a.y + (p0.y + p1.y) * inv,
                a.z + (p0.z + p1.z) * inv, a.w + (p0.w + p1.w) * inv};
    float s = v.x + v.y + v.z + v.w;
#pragma unroll
    for (int off = 1; off < 64; off <<= 1) s += __shfl_xor(s, off, 64);
    float mu = s * (1.f / HID_);
    float4 d = {v.x - mu, v.y - mu, v.z - mu, v.w - mu};
    float s2 = d.x * d.x + d.y * d.y + d.z * d.z + d.w * d.w;
#pragma unroll
    for (int off = 1; off < 64; off <<= 1) s2 += __shfl_xor(s2, off, 64);
    float rs = rsqrtf(s2 * (1.f / HID_) + EPS_);
    float4 gg = *(const float4*)&g[lane * 4];
    float4 bbv = *(const float4*)&bb[lane * 4];
    float4 res;
    res.x = d.x * rs * gg.x + bbv.x;
    res.y = d.y * rs * gg.y + bbv.y;
    res.z = d.z * rs * gg.z + bbv.z;
    res.w = d.w * rs * gg.w + bbv.w;
    *(float4*)&h[row * HID_ + lane * 4] = res;
    ushort4 pk = {f2bf(res.x), f2bf(res.y), f2bf(res.z), f2bf(res.w)};
    *(ushort4*)&hbf[row * HID_ + lane * 4] = pk;
}

// ---------------------------------------------------------------------------
extern "C" void kernel_launch(void* const* d_in, const int* in_sizes, int n_in,
                              void* d_out, int out_size, void* d_ws, size_t ws_size,
                              hipStream_t stream) {
    const float* X_obs = (const float*)d_in[0];
    const float* mask  = (const float*)d_in[1];
    const float* W_in  = (const float*)d_in[2];
    const float* b_in  = (const float*)d_in[3];
    const float* gat_W = (const float*)d_in[4];
    const float* gat_a = (const float*)d_in[5];
    const float* ln_g  = (const float*)d_in[6];
    const float* ln_b  = (const float*)d_in[7];
    const float* W_out = (const float*)d_in[8];
    const float* b_out = (const float*)d_in[9];
    float* out = (float*)d_out;

    // Workspace layout (~35 MB of the 256 MB d_ws):
    //  [0,16M):   Ain bf16 (M x 1024); dead after g1, then:
    //             hwT bf16 [32][64][1024] at [0,4M), pacc fp32 [2][M][256] at [4,20M)
    //  [20M,+):   pden fp32 [2][M][4] (256 KB)
    //  [21M,29M): hbuf fp32 (M x 256)
    //  [29M,33M): hbf bf16 (M x 256)
    //  [33M,+):   Wt_in, Wcat, WtO (bf16), slb/srb (fp32), rmaxkey (uint[64])
    char* base = (char*)d_ws;
    unsigned short* Ain  = (unsigned short*)base;
    unsigned short* hwT  = (unsigned short*)base;
    float* pacc = (float*)(base + (4u << 20));
    float* pden = (float*)(base + (20u << 20));
    float* hbuf = (float*)(base + (21u << 20));
    unsigned short* hbf   = (unsigned short*)(base + (29u << 20));
    unsigned short* Wt_in = (unsigned short*)(base + (33u << 20));
    unsigned short* Wcat  = Wt_in + (size_t)HID_ * KIN_;        // 256*1024
    unsigned short* WtO   = Wcat + (size_t)NL_ * HID_ * HID_;   // 2*256*256
    float* slb = (float*)(WtO + (size_t)T_ * HID_);             // 32*1024
    float* srb = slb + B_ * NH_ * D_;
    unsigned int* rmaxkey = (unsigned int*)(srb + B_ * NH_ * D_);  // [2][32]

    prep_k<<<2560, 256, 0, stream>>>(X_obs, mask, W_in, gat_W, W_out,
                                     Ain, Wt_in, Wcat, WtO, rmaxkey);

    // h = [X_mean|mask] @ W_in + b_in   (8192x1024)@(1024x256), fp32+bf16 out
    gemm_bf16_k<1><<<dim3(HID_ / 64, M_ / 64), 256, 0, stream>>>(
        Ain, Wt_in, b_in, hbuf, hbf, nullptr, nullptr, nullptr, nullptr,
        HID_, KIN_);

    for (int l = 0; l < NL_; l++) {
        // hW = h @ Wcat[l] -> hwT bf16 + fused s_l/s_r/rmax
        gemm_bf16_k<2><<<dim3(HID_ / 64, M_ / 64), 256, 0, stream>>>(
            hbf, Wcat + (size_t)l * HID_ * HID_, nullptr, nullptr, hwT,
            gat_a + (size_t)l * NH_ * 2 * OUT_, slb, srb, rmaxkey + l * 32,
            HID_, HID_);
        attn_k<<<dim3(B_ * NH_, D_ / 64, 2), 256, 0, stream>>>(
            hwT, slb, srb, rmaxkey + l * 32, pacc, pden);
        addln_k<<<M_ / 4, 256, 0, stream>>>(hbuf, pacc, pden,
                                            ln_g + (size_t)l * HID_,
                                            ln_b + (size_t)l * HID_, hbf);
    }

    // out = h @ W_out + b_out  (8192x256)@(256x512), fp32 out
    gemm_bf16_k<0><<<dim3(T_ / 64, M_ / 64), 256, 0, stream>>>(
        hbf, WtO, b_out, out, nullptr, nullptr, nullptr, nullptr, nullptr,
        T_, HID_);
}